// Round 10
// baseline (183.114 us; speedup 1.0000x reference)
//
#include <hip/hip_runtime.h>
#include <hip/hip_bf16.h>
#include <math.h>

// Problem constants (fixed by setup_inputs)
#define CIN      8
#define H_IN     100
#define W_IN     136
#define NPIX     (H_IN * W_IN)       // 13600
#define OH       (2 * H_IN)          // 200
#define OW       (2 * W_IN)          // 272
#define ONPIX    (OH * OW)           // 54400
#define NPARAMS  169
#define EPSV     1e-5f
#define NSLICE   4                   // row-slices per instance
#define KG4      34                  // 136/4 col-groups of 4 src px
#define KGROUPS  34                  // 272/8 output col-groups
#define TASKS_B  (25 * KGROUPS)      // 850 phase-B tasks per slice

// param layout: w0[8][10] @0, w1[8][8] @80, w2[8] @144, b0 @152, b1 @160, b2 @168

typedef float v2f __attribute__((ext_vector_type(2)));
#define V2S(x) ((v2f){(x), (x)})

__device__ __forceinline__ float sigmoidf_fast(float x) {
    float e = __expf(-x);
    return __builtin_amdgcn_rcpf(1.f + e);
}

// R5/R8/R9 all ~182 us across 2/3/4-waves-per-SIMD variants -> kernel is
// VALU-ISSUE-bound, not latency-bound. This round: fp32 math as float2
// vectors -> V_PK_FMA_F32 (VOP3P, 2 FMA/lane/inst) to halve the issue
// stream. Peak regs ~72 -> (256,3) natural fit (R8-proven occupancy).
__global__ __launch_bounds__(256, 3)
void mask_head_fused(const float* __restrict__ mask_feats,   // [N,8,100,136]
                     const float* __restrict__ params,       // [n,169]
                     const float* __restrict__ locs,         // [n,2]
                     const float* __restrict__ gt,           // [n,1,200,272]
                     const int*   __restrict__ im_inds,      // [n]
                     const int*   __restrict__ fpn_levels,   // [n]
                     float*       __restrict__ partials)     // [n*4][3]
{
    const int inst  = blockIdx.x >> 2;
    const int slice = blockIdx.x & 3;
    const int tid   = threadIdx.x;

    // src rows for this slice: max(25*slice-1,0) .. 25*slice+24
    const int r_start = (slice == 0) ? 0 : 25 * slice - 1;
    const int nrows   = (slice == 0) ? 25 : 26;
    const int ntask   = nrows * KG4;               // <= 884

    __shared__ float s_logit[26 * W_IN];           // 14144 B
    __shared__ float s_red[12];

    // Block-uniform weight pointer -> scalar K$ loads, zero VALU/LDS cost.
    const float* __restrict__ wp = params + (size_t)inst * NPARAMS;

    const int   im  = im_inds[inst];
    const int   lvl = fpn_levels[inst];
    const float inv_soi = exp2f(-(float)(3 + lvl));  // SOI = 8*2^lvl, exact
    const float lx = locs[inst * 2 + 0];
    const float ly = locs[inst * 2 + 1];
    const float dx8 = 8.f * inv_soi;

    const float* feat = mask_feats + (size_t)im * (CIN * NPIX);
    const int goff = r_start * W_IN;   // global pixel offset of local row 0

    // ---------------- Phase A: logits -> LDS (packed fp32) ----------------
    // Task = 4 consecutive px in one row, processed as TWO float2 pairs.
    // All 8 channel float4s in flight (32 dedicated regs); MLP math in v2f
    // so each inst is a v_pk_fma_f32 (2 px at once). Layers 1+2 fused.
    #pragma unroll 1
    for (int it = 0; it < 4; ++it) {
        const int t = it * 256 + tid;
        const bool valid = t < ntask;
        const int tc = valid ? t : ntask - 1;
        const int r  = tc / KG4;                   // local row
        const int k  = tc - r * KG4;               // col-group
        const int lpx = r * W_IN + 4 * k;
        const float* fb = feat + (goff + lpx);

        // all 8 channel loads in flight together
        float4 f[8];
        #pragma unroll
        for (int c = 0; c < CIN; ++c)
            f[c] = *(const float4*)(fb + c * NPIX);

        const float in00 = (lx - (float)(32 * k + 4)) * inv_soi;
        const float in1  = (ly - (float)((r_start + r) * 8 + 4)) * inv_soi;
        const v2f in0l = {in00, in00 - dx8};
        const v2f in0h = {in00 - 2.f * dx8, in00 - 3.f * dx8};

        v2f o_lo, o_hi;

#define DO_PAIR(RES, IN0, CX, CY)                                             \
        {                                                                     \
            v2f aj[8];                                                        \
            _Pragma("unroll")                                                 \
            for (int o = 0; o < 8; ++o)                                       \
                aj[o] = __builtin_elementwise_fma(                            \
                    V2S(wp[o * 10]), IN0,                                     \
                    V2S(fmaf(wp[o * 10 + 1], in1, wp[152 + o])));             \
            _Pragma("unroll")                                                 \
            for (int c = 0; c < 8; ++c) {                                     \
                const v2f fv = {f[c].CX, f[c].CY};                            \
                _Pragma("unroll")                                             \
                for (int o = 0; o < 8; ++o)                                   \
                    aj[o] = __builtin_elementwise_fma(                        \
                        V2S(wp[o * 10 + 2 + c]), fv, aj[o]);                  \
            }                                                                 \
            _Pragma("unroll")                                                 \
            for (int o = 0; o < 8; ++o)                                       \
                aj[o] = __builtin_elementwise_max(aj[o], V2S(0.f));           \
            v2f acc = V2S(wp[168]);                                           \
            _Pragma("unroll")                                                 \
            for (int o = 0; o < 8; ++o) {                                     \
                v2f tt = V2S(wp[160 + o]);                                    \
                _Pragma("unroll")                                             \
                for (int i = 0; i < 8; ++i)                                   \
                    tt = __builtin_elementwise_fma(                           \
                        V2S(wp[80 + o * 8 + i]), aj[i], tt);                  \
                acc = __builtin_elementwise_fma(                              \
                    V2S(wp[144 + o]),                                         \
                    __builtin_elementwise_max(tt, V2S(0.f)), acc);            \
            }                                                                 \
            RES = acc;                                                        \
        }

        DO_PAIR(o_lo, in0l, x, y)
        DO_PAIR(o_hi, in0h, z, w)
#undef DO_PAIR

        if (valid) {
            float4 ov = {o_lo.x, o_lo.y, o_hi.x, o_hi.y};
            *(float4*)(s_logit + lpx) = ov;   // 16B-aligned
        }
    }

    __syncthreads();

    // ---------------- Phase B: structured x2 upsample + sigmoid + dice ----------
    // Output row 2p   = avg(src row p-1, src row p)   (p=0: src row 0)
    // Output row 2p+1 = src row p
    // Output cols: o[2j]=avg of adjacent src cols, o[2j+1]=src col (left edge clamp)
    // Accumulators packed as v2f (3 pk-fma per 2 px instead of 6 fma).
    v2f inter2 = V2S(0.f), ssum2 = V2S(0.f), tsum2 = V2S(0.f);
    const float* gtp = gt + (size_t)inst * ONPIX;
    const int pair_base = 25 * slice;

    #pragma unroll 1
    for (int base = 0; base < TASKS_B; base += 256) {
        const int task = base + tid;
        if (task < TASKS_B) {
            const int pl = task / KGROUPS;
            const int k  = task - pl * KGROUPS;
            const int pg = pair_base + pl;
            const int er = pg - r_start;                       // exact src row (local)
            const int pr = (pg > 0 ? pg - 1 : 0) - r_start;    // prev src row (local)
            const float* E = s_logit + er * W_IN;
            const float* P = s_logit + pr * W_IN;
            const int c0  = 4 * k;
            const int cm1 = (k > 0) ? c0 - 1 : 0;

            // issue all loads upfront
            const float* g0 = gtp + (size_t)(2 * pg) * OW + 8 * k;
            const float4 ga = *(const float4*)(g0);            // avg row, cols 0-3
            const float4 gb = *(const float4*)(g0 + 4);        // avg row, cols 4-7
            const float4 gc = *(const float4*)(g0 + OW);       // exact row, cols 0-3
            const float4 gd = *(const float4*)(g0 + OW + 4);   // exact row, cols 4-7
            const float4 e4 = *(const float4*)(E + c0);
            const float  em = E[cm1];
            const float4 p4 = *(const float4*)(P + c0);
            const float  pm = P[cm1];

            const float ecur[4] = {e4.x, e4.y, e4.z, e4.w};
            const float pcur[4] = {p4.x, p4.y, p4.z, p4.w};
            const float gav[8] = {ga.x, ga.y, ga.z, ga.w, gb.x, gb.y, gb.z, gb.w};
            const float gex[8] = {gc.x, gc.y, gc.z, gc.w, gd.x, gd.y, gd.z, gd.w};

            float Se_prev = em;
            float Sa_prev = 0.5f * (em + pm);
            #pragma unroll
            for (int j = 0; j < 4; ++j) {
                const float Se = ecur[j];
                const float Sa = 0.5f * (ecur[j] + pcur[j]);
                {
                    const v2f s = {sigmoidf_fast(0.5f * (Sa_prev + Sa)),
                                   sigmoidf_fast(Sa)};
                    const v2f t = {gav[2 * j], gav[2 * j + 1]};
                    inter2 = __builtin_elementwise_fma(s, t, inter2);
                    ssum2  = __builtin_elementwise_fma(s, s, ssum2);
                    tsum2  = __builtin_elementwise_fma(t, t, tsum2);
                }
                {
                    const v2f s = {sigmoidf_fast(0.5f * (Se_prev + Se)),
                                   sigmoidf_fast(Se)};
                    const v2f t = {gex[2 * j], gex[2 * j + 1]};
                    inter2 = __builtin_elementwise_fma(s, t, inter2);
                    ssum2  = __builtin_elementwise_fma(s, s, ssum2);
                    tsum2  = __builtin_elementwise_fma(t, t, tsum2);
                }
                Se_prev = Se;
                Sa_prev = Sa;
            }
        }
    }

    float inter = inter2.x + inter2.y;
    float ssum  = ssum2.x + ssum2.y;
    float tsum  = tsum2.x + tsum2.y;

    // block reduction (4 waves of 64)
    #pragma unroll
    for (int off = 32; off > 0; off >>= 1) {
        inter += __shfl_down(inter, off, 64);
        ssum  += __shfl_down(ssum,  off, 64);
        tsum  += __shfl_down(tsum,  off, 64);
    }
    const int wid = tid >> 6;
    if ((tid & 63) == 0) {
        s_red[wid * 3 + 0] = inter;
        s_red[wid * 3 + 1] = ssum;
        s_red[wid * 3 + 2] = tsum;
    }
    __syncthreads();
    if (tid == 0) {
        float I = 0.f, S = 0.f, T = 0.f;
        #pragma unroll
        for (int w = 0; w < 4; ++w) {
            I += s_red[w * 3 + 0];
            S += s_red[w * 3 + 1];
            T += s_red[w * 3 + 2];
        }
        partials[blockIdx.x * 3 + 0] = I;
        partials[blockIdx.x * 3 + 1] = S;
        partials[blockIdx.x * 3 + 2] = T;
    }
}

__global__ __launch_bounds__(512)
void loss_mean_kernel(const float* __restrict__ partials, float* __restrict__ out, int n)
{
    __shared__ float s_red[8];
    float v = 0.f;
    for (int i = threadIdx.x; i < n; i += 512) {
        float I = 0.f, S = 0.f, T = 0.f;
        #pragma unroll
        for (int s = 0; s < NSLICE; ++s) {
            const float* p = partials + (size_t)(i * NSLICE + s) * 3;
            I += p[0];
            S += p[1];
            T += p[2];
        }
        v += 1.f - 2.f * I / (S + T + EPSV);
    }
    #pragma unroll
    for (int off = 32; off > 0; off >>= 1) v += __shfl_down(v, off, 64);
    const int wid = threadIdx.x >> 6;
    if ((threadIdx.x & 63) == 0) s_red[wid] = v;
    __syncthreads();
    if (threadIdx.x == 0) {
        float s = 0.f;
        #pragma unroll
        for (int w = 0; w < 8; ++w) s += s_red[w];
        out[0] = s / (float)n;
    }
}

extern "C" void kernel_launch(void* const* d_in, const int* in_sizes, int n_in,
                              void* d_out, int out_size, void* d_ws, size_t ws_size,
                              hipStream_t stream)
{
    const float* mask_feats = (const float*)d_in[0];
    const float* params     = (const float*)d_in[1];
    const float* locs       = (const float*)d_in[2];
    const float* gt         = (const float*)d_in[3];
    const int*   im_inds    = (const int*)d_in[4];
    const int*   fpn_levels = (const int*)d_in[5];
    // d_in[6] = mask_feat_stride (always 8 for this problem)

    const int n = in_sizes[4];          // 500 instances
    float* partials = (float*)d_ws;     // n*NSLICE*3 floats

    mask_head_fused<<<n * NSLICE, 256, 0, stream>>>(mask_feats, params, locs, gt,
                                                    im_inds, fpn_levels, partials);
    loss_mean_kernel<<<1, 512, 0, stream>>>(partials, (float*)d_out, n);
}

// Round 11
// 181.808 us; speedup vs baseline: 1.0072x; 1.0072x over previous
//
#include <hip/hip_runtime.h>
#include <hip/hip_bf16.h>
#include <math.h>

// Problem constants (fixed by setup_inputs)
#define CIN      8
#define H_IN     100
#define W_IN     136
#define NPIX     (H_IN * W_IN)       // 13600
#define OH       (2 * H_IN)          // 200
#define OW       (2 * W_IN)          // 272
#define ONPIX    (OH * OW)           // 54400
#define NPARAMS  169
#define EPSV     1e-5f
#define NSLICE   4                   // row-slices per instance
#define KG4      34                  // 136/4 col-groups of 4 src px
#define KGROUPS  34                  // 272/8 output col-groups
#define TASKS_B  (25 * KGROUPS)      // 850 phase-B tasks per slice

// param layout: w0[8][10] @0, w1[8][8] @80, w2[8] @144, b0 @152, b1 @160, b2 @168

__device__ __forceinline__ float sigmoidf_fast(float x) {
    float e = __expf(-x);
    return __builtin_amdgcn_rcpf(1.f + e);
}

// Session findings: R5/R8/R9/R10 all ~182 us total across 2/3/4 waves/SIMD and
// scalar/packed fp32 -> not occupancy- or pk-limited. This round targets SGPR
// weight-set churn: STAGE-ORDERED weights so each stage's uniform weight set
// (88 for layer 0, 81 for layers 1+2) fits in free SGPRs -> s_loads once per
// stage, not per pixel. Peak VGPR ~75 -> (256,3).
__global__ __launch_bounds__(256, 3)
void mask_head_fused(const float* __restrict__ mask_feats,   // [N,8,100,136]
                     const float* __restrict__ params,       // [n,169]
                     const float* __restrict__ locs,         // [n,2]
                     const float* __restrict__ gt,           // [n,1,200,272]
                     const int*   __restrict__ im_inds,      // [n]
                     const int*   __restrict__ fpn_levels,   // [n]
                     float*       __restrict__ partials)     // [n*4][3]
{
    const int inst  = blockIdx.x >> 2;
    const int slice = blockIdx.x & 3;
    const int tid   = threadIdx.x;

    // src rows for this slice: max(25*slice-1,0) .. 25*slice+24
    const int r_start = (slice == 0) ? 0 : 25 * slice - 1;
    const int nrows   = (slice == 0) ? 25 : 26;
    const int ntask   = nrows * KG4;               // <= 884

    __shared__ float s_logit[26 * W_IN];           // 14144 B
    __shared__ float s_red[12];

    // Block-uniform weight pointer -> scalar K$ loads, zero VALU/LDS cost.
    const float* __restrict__ wp = params + (size_t)inst * NPARAMS;

    const int   im  = im_inds[inst];
    const int   lvl = fpn_levels[inst];
    const float inv_soi = exp2f(-(float)(3 + lvl));  // SOI = 8*2^lvl, exact
    const float lx = locs[inst * 2 + 0];
    const float ly = locs[inst * 2 + 1];
    const float dx8 = 8.f * inv_soi;

    const float* feat = mask_feats + (size_t)im * (CIN * NPIX);
    const int goff = r_start * W_IN;   // global pixel offset of local row 0

    // ---------------- Phase A: logits -> LDS (stage-ordered weights) ----------
    // Task = 4 consecutive px in one row. Stage 0 consumes ONLY w0/b0 (88
    // uniform floats -> fits SGPRs); stage 1 consumes ONLY w1/w2/b1/b2 (81).
    #pragma unroll 1
    for (int it = 0; it < 4; ++it) {
        const int t = it * 256 + tid;
        const bool valid = t < ntask;
        const int tc = valid ? t : ntask - 1;
        const int r  = tc / KG4;                   // local row
        const int k  = tc - r * KG4;               // col-group
        const int lpx = r * W_IN + 4 * k;
        const float* fb = feat + (goff + lpx);

        // all 8 channel loads in flight together (32 dedicated regs)
        float4 f[8];
        #pragma unroll
        for (int c = 0; c < CIN; ++c)
            f[c] = *(const float4*)(fb + c * NPIX);

        float in0[4];
        in0[0] = (lx - (float)(32 * k + 4)) * inv_soi;
        in0[1] = in0[0] - dx8;
        in0[2] = in0[1] - dx8;
        in0[3] = in0[2] - dx8;
        const float in1 = (ly - (float)((r_start + r) * 8 + 4)) * inv_soi;

        // ---- stage 0: layer 0 (10 -> 8) + relu, for all 4 px. live: w0,b0 ----
        float a[8][4];
        #pragma unroll
        for (int o = 0; o < 8; ++o) {
            const float base = fmaf(wp[o * 10 + 1], in1, wp[152 + o]);
            const float w0 = wp[o * 10];
            #pragma unroll
            for (int j = 0; j < 4; ++j)
                a[o][j] = fmaf(w0, in0[j], base);
        }
        #pragma unroll
        for (int c = 0; c < 8; ++c) {
            const float fv[4] = {f[c].x, f[c].y, f[c].z, f[c].w};
            #pragma unroll
            for (int o = 0; o < 8; ++o) {
                const float w = wp[o * 10 + 2 + c];
                #pragma unroll
                for (int j = 0; j < 4; ++j)
                    a[o][j] = fmaf(w, fv[j], a[o][j]);
            }
        }
        #pragma unroll
        for (int o = 0; o < 8; ++o)
            #pragma unroll
            for (int j = 0; j < 4; ++j)
                a[o][j] = fmaxf(a[o][j], 0.f);

        // ---- stage 1: layers 1+2 fused, for all 4 px. live: w1,w2,b1,b2 ----
        float o4[4];
        #pragma unroll
        for (int j = 0; j < 4; ++j) o4[j] = wp[168];
        #pragma unroll
        for (int o = 0; o < 8; ++o) {
            const float b1 = wp[160 + o];
            const float w2 = wp[144 + o];
            float tt[4] = {b1, b1, b1, b1};
            #pragma unroll
            for (int i = 0; i < 8; ++i) {
                const float w = wp[80 + o * 8 + i];
                #pragma unroll
                for (int j = 0; j < 4; ++j)
                    tt[j] = fmaf(w, a[i][j], tt[j]);
            }
            #pragma unroll
            for (int j = 0; j < 4; ++j)
                o4[j] = fmaf(w2, fmaxf(tt[j], 0.f), o4[j]);
        }

        if (valid) {
            float4 ov = {o4[0], o4[1], o4[2], o4[3]};
            *(float4*)(s_logit + lpx) = ov;   // 16B-aligned
        }
    }

    __syncthreads();

    // ---------------- Phase B: structured x2 upsample + sigmoid + dice ----------
    // Output row 2p   = avg(src row p-1, src row p)   (p=0: src row 0)
    // Output row 2p+1 = src row p
    // Output cols: o[2j]=avg of adjacent src cols, o[2j+1]=src col (left edge clamp)
    float inter = 0.f, ssum = 0.f, tsum = 0.f;
    const float* gtp = gt + (size_t)inst * ONPIX;
    const int pair_base = 25 * slice;

    #pragma unroll 1
    for (int base = 0; base < TASKS_B; base += 256) {
        const int task = base + tid;
        if (task < TASKS_B) {
            const int pl = task / KGROUPS;
            const int k  = task - pl * KGROUPS;
            const int pg = pair_base + pl;
            const int er = pg - r_start;                       // exact src row (local)
            const int pr = (pg > 0 ? pg - 1 : 0) - r_start;    // prev src row (local)
            const float* E = s_logit + er * W_IN;
            const float* P = s_logit + pr * W_IN;
            const int c0  = 4 * k;
            const int cm1 = (k > 0) ? c0 - 1 : 0;

            // issue all loads upfront
            const float* g0 = gtp + (size_t)(2 * pg) * OW + 8 * k;
            const float4 ga = *(const float4*)(g0);            // avg row, cols 0-3
            const float4 gb = *(const float4*)(g0 + 4);        // avg row, cols 4-7
            const float4 gc = *(const float4*)(g0 + OW);       // exact row, cols 0-3
            const float4 gd = *(const float4*)(g0 + OW + 4);   // exact row, cols 4-7
            const float4 e4 = *(const float4*)(E + c0);
            const float  em = E[cm1];
            const float4 p4 = *(const float4*)(P + c0);
            const float  pm = P[cm1];

            const float ecur[4] = {e4.x, e4.y, e4.z, e4.w};
            const float pcur[4] = {p4.x, p4.y, p4.z, p4.w};
            const float gav[8] = {ga.x, ga.y, ga.z, ga.w, gb.x, gb.y, gb.z, gb.w};
            const float gex[8] = {gc.x, gc.y, gc.z, gc.w, gd.x, gd.y, gd.z, gd.w};

            float Se_prev = em;
            float Sa_prev = 0.5f * (em + pm);
            #pragma unroll
            for (int j = 0; j < 4; ++j) {
                const float Se = ecur[j];
                const float Sa = 0.5f * (ecur[j] + pcur[j]);
                {
                    float s = sigmoidf_fast(0.5f * (Sa_prev + Sa));
                    float t2 = gav[2 * j];
                    inter = fmaf(s, t2, inter); ssum = fmaf(s, s, ssum); tsum = fmaf(t2, t2, tsum);
                    s = sigmoidf_fast(Sa);
                    t2 = gav[2 * j + 1];
                    inter = fmaf(s, t2, inter); ssum = fmaf(s, s, ssum); tsum = fmaf(t2, t2, tsum);
                }
                {
                    float s = sigmoidf_fast(0.5f * (Se_prev + Se));
                    float t2 = gex[2 * j];
                    inter = fmaf(s, t2, inter); ssum = fmaf(s, s, ssum); tsum = fmaf(t2, t2, tsum);
                    s = sigmoidf_fast(Se);
                    t2 = gex[2 * j + 1];
                    inter = fmaf(s, t2, inter); ssum = fmaf(s, s, ssum); tsum = fmaf(t2, t2, tsum);
                }
                Se_prev = Se;
                Sa_prev = Sa;
            }
        }
    }

    // block reduction (4 waves of 64)
    #pragma unroll
    for (int off = 32; off > 0; off >>= 1) {
        inter += __shfl_down(inter, off, 64);
        ssum  += __shfl_down(ssum,  off, 64);
        tsum  += __shfl_down(tsum,  off, 64);
    }
    const int wid = tid >> 6;
    if ((tid & 63) == 0) {
        s_red[wid * 3 + 0] = inter;
        s_red[wid * 3 + 1] = ssum;
        s_red[wid * 3 + 2] = tsum;
    }
    __syncthreads();
    if (tid == 0) {
        float I = 0.f, S = 0.f, T = 0.f;
        #pragma unroll
        for (int w = 0; w < 4; ++w) {
            I += s_red[w * 3 + 0];
            S += s_red[w * 3 + 1];
            T += s_red[w * 3 + 2];
        }
        partials[blockIdx.x * 3 + 0] = I;
        partials[blockIdx.x * 3 + 1] = S;
        partials[blockIdx.x * 3 + 2] = T;
    }
}

__global__ __launch_bounds__(512)
void loss_mean_kernel(const float* __restrict__ partials, float* __restrict__ out, int n)
{
    __shared__ float s_red[8];
    float v = 0.f;
    for (int i = threadIdx.x; i < n; i += 512) {
        float I = 0.f, S = 0.f, T = 0.f;
        #pragma unroll
        for (int s = 0; s < NSLICE; ++s) {
            const float* p = partials + (size_t)(i * NSLICE + s) * 3;
            I += p[0];
            S += p[1];
            T += p[2];
        }
        v += 1.f - 2.f * I / (S + T + EPSV);
    }
    #pragma unroll
    for (int off = 32; off > 0; off >>= 1) v += __shfl_down(v, off, 64);
    const int wid = threadIdx.x >> 6;
    if ((threadIdx.x & 63) == 0) s_red[wid] = v;
    __syncthreads();
    if (threadIdx.x == 0) {
        float s = 0.f;
        #pragma unroll
        for (int w = 0; w < 8; ++w) s += s_red[w];
        out[0] = s / (float)n;
    }
}

extern "C" void kernel_launch(void* const* d_in, const int* in_sizes, int n_in,
                              void* d_out, int out_size, void* d_ws, size_t ws_size,
                              hipStream_t stream)
{
    const float* mask_feats = (const float*)d_in[0];
    const float* params     = (const float*)d_in[1];
    const float* locs       = (const float*)d_in[2];
    const float* gt         = (const float*)d_in[3];
    const int*   im_inds    = (const int*)d_in[4];
    const int*   fpn_levels = (const int*)d_in[5];
    // d_in[6] = mask_feat_stride (always 8 for this problem)

    const int n = in_sizes[4];          // 500 instances
    float* partials = (float*)d_ws;     // n*NSLICE*3 floats

    mask_head_fused<<<n * NSLICE, 256, 0, stream>>>(mask_feats, params, locs, gt,
                                                    im_inds, fpn_levels, partials);
    loss_mean_kernel<<<1, 512, 0, stream>>>(partials, (float*)d_out, n);
}